// Round 1
// baseline (1156.148 us; speedup 1.0000x reference)
//
#include <hip/hip_runtime.h>

#define NN 50000
#define NE 800000

typedef __attribute__((ext_vector_type(8))) short short8;
typedef __attribute__((ext_vector_type(4))) float floatx4;

__device__ __forceinline__ unsigned short f2b(float f){
  unsigned u = __float_as_uint(f);
  u += 0x7fffu + ((u >> 16) & 1u);
  return (unsigned short)(u >> 16);
}
__device__ __forceinline__ float blo(unsigned u){ return __uint_as_float(u << 16); }
__device__ __forceinline__ float bhi(unsigned u){ return __uint_as_float(u & 0xffff0000u); }

// ---------------- CSR build ----------------
__global__ __launch_bounds__(256) void k_hist(const int* __restrict__ v, int* __restrict__ cnt){
  int e = blockIdx.x * 256 + threadIdx.x;
  if(e < NE) atomicAdd(&cnt[v[e]], 1);
}

__global__ __launch_bounds__(512) void k_scanA(const int* __restrict__ cnt,
                                               int* __restrict__ rowptr,
                                               int* __restrict__ part){
  __shared__ int lds[512];
  int t = threadIdx.x;
  int i = blockIdx.x * 512 + t;
  int x = (i < NN) ? cnt[i] : 0;
  lds[t] = x;
  __syncthreads();
  for(int o = 1; o < 512; o <<= 1){
    int y = (t >= o) ? lds[t - o] : 0;
    __syncthreads();
    lds[t] += y;
    __syncthreads();
  }
  if(i < NN) rowptr[i] = lds[t] - x;     // block-local exclusive prefix
  if(t == 511) part[blockIdx.x] = lds[511];
}

__global__ void k_scanB(int* __restrict__ part, int* __restrict__ rowptr){
  if(threadIdx.x == 0 && blockIdx.x == 0){
    int run = 0;
    for(int b = 0; b < 98; b++){ int tt = part[b]; part[b] = run; run += tt; }
    rowptr[NN] = run;   // = NE
  }
}

__global__ __launch_bounds__(512) void k_scanC(int* __restrict__ rowptr,
                                               const int* __restrict__ part,
                                               int* __restrict__ cursor){
  int i = blockIdx.x * 512 + threadIdx.x;
  if(i < NN){
    int val = rowptr[i] + part[blockIdx.x];
    rowptr[i] = val;
    cursor[i] = val;
  }
}

__global__ __launch_bounds__(256) void k_fill(const int* __restrict__ u, const int* __restrict__ v,
                                              int* __restrict__ cursor, int2* __restrict__ ebuf){
  int e = blockIdx.x * 256 + threadIdx.x;
  if(e < NE){
    int pos = atomicAdd(&cursor[v[e]], 1);
    ebuf[pos] = make_int2(u[e], e);
  }
}

// ---------------- fp32 -> bf16 convert (nfeats) ----------------
__global__ __launch_bounds__(256) void k_cvt4(const float4* __restrict__ in,
                                              unsigned short* __restrict__ outp, int n4){
  int i = blockIdx.x * 256 + threadIdx.x;
  if(i >= n4) return;
  float4 vv = in[i];
  unsigned a = (unsigned)f2b(vv.x) | ((unsigned)f2b(vv.y) << 16);
  unsigned b = (unsigned)f2b(vv.z) | ((unsigned)f2b(vv.w) << 16);
  ((uint2*)outp)[i] = make_uint2(a, b);
}

// ---------------- weight swizzle to B-fragment layout ----------------
// layout: dst[((k>>5)*N + n)*40 + (k&31)]  (stride 40 halves = 80B per slot, 16B aligned)
__global__ __launch_bounds__(256) void k_wswz_dir(const float* __restrict__ W,
                                                  unsigned short* __restrict__ dst, int K, int N){
  int i = blockIdx.x * 256 + threadIdx.x;
  if(i >= K * N) return;
  int k = i / N, n = i % N;
  dst[((size_t)((k >> 5) * N + n)) * 40 + (k & 31)] = f2b(W[i]);
}

// W: [256,128] -> B: [128,256] with B[k][n] = W[k + (n>=128)*128][n&127]
__global__ __launch_bounds__(256) void k_wswz_edge(const float* __restrict__ W,
                                                   unsigned short* __restrict__ dst){
  int i = blockIdx.x * 256 + threadIdx.x;
  if(i >= 128 * 256) return;
  int k = i >> 8, n = i & 255;
  float val = W[(size_t)(k + ((n >> 7) << 7)) * 128 + (n & 127)];
  dst[((size_t)((k >> 5) * 256 + n)) * 40 + (k & 31)] = f2b(val);
}

// ---------------- layer-1 aggregation ----------------
// msg = concat(nfeats[u] (64), efeats[e] (64)); mean over incoming edges of node.
// 64 lanes per node, 2 cols/lane. Output bf16 [NN,128].
__global__ __launch_bounds__(256) void k_agg1(const int* __restrict__ rowptr,
                                              const int2* __restrict__ ebuf,
                                              const unsigned short* __restrict__ nfb,
                                              const float* __restrict__ ef,
                                              unsigned short* __restrict__ hneigh1){
  int node = blockIdx.x * 4 + (threadIdx.x >> 6);
  int l = threadIdx.x & 63;
  int beg = rowptr[node], end = rowptr[node + 1];
  float a0 = 0.f, a1 = 0.f;
  if(l < 32){
    const unsigned short* base = nfb + 2 * l;
    for(int i = beg; i < end; i++){
      int s = ebuf[i].x;
      unsigned t = *(const unsigned*)(base + (size_t)s * 64);
      a0 += blo(t); a1 += bhi(t);
    }
  } else {
    const float* base = ef + 2 * (l - 32);
    for(int i = beg; i < end; i++){
      int e = ebuf[i].y;
      float2 t = *(const float2*)(base + (size_t)e * 64);
      a0 += t.x; a1 += t.y;
    }
  }
  float inv = 1.f / fmaxf((float)(end - beg), 1.f);
  unsigned o = (unsigned)f2b(a0 * inv) | ((unsigned)f2b(a1 * inv) << 16);
  *(unsigned*)(hneigh1 + (size_t)node * 128 + 2 * l) = o;
}

// ---------------- layer-2 aggregation ----------------
// msg = concat(hn1[u] (128), relu(P1[u]+Q1[v]+b1e) (128)); mean over incoming edges.
// 64 lanes per node, 4 cols/lane. Output bf16 [NN,256].
__global__ __launch_bounds__(256) void k_agg2(const int* __restrict__ rowptr,
                                              const int2* __restrict__ ebuf,
                                              const unsigned short* __restrict__ hn1,
                                              const unsigned short* __restrict__ PQ1,
                                              const float* __restrict__ b1e,
                                              unsigned short* __restrict__ hneigh2){
  int node = blockIdx.x * 4 + (threadIdx.x >> 6);
  int l = threadIdx.x & 63;
  int beg = rowptr[node], end = rowptr[node + 1];
  float a0 = 0.f, a1 = 0.f, a2 = 0.f, a3 = 0.f;
  if(l < 32){
    const unsigned short* base = hn1 + 4 * l;
    for(int i = beg; i < end; i++){
      int s = ebuf[i].x;
      uint2 t = *(const uint2*)(base + (size_t)s * 128);
      a0 += blo(t.x); a1 += bhi(t.x); a2 += blo(t.y); a3 += bhi(t.y);
    }
  } else {
    int c = 4 * (l - 32);
    uint2 qq = *(const uint2*)(PQ1 + (size_t)node * 256 + 128 + c);
    float q0 = blo(qq.x) + b1e[c];
    float q1 = bhi(qq.x) + b1e[c + 1];
    float q2 = blo(qq.y) + b1e[c + 2];
    float q3 = bhi(qq.y) + b1e[c + 3];
    const unsigned short* base = PQ1 + c;
    for(int i = beg; i < end; i++){
      int s = ebuf[i].x;
      uint2 t = *(const uint2*)(base + (size_t)s * 256);
      a0 += fmaxf(blo(t.x) + q0, 0.f);
      a1 += fmaxf(bhi(t.x) + q1, 0.f);
      a2 += fmaxf(blo(t.y) + q2, 0.f);
      a3 += fmaxf(bhi(t.y) + q3, 0.f);
    }
  }
  float inv = 1.f / fmaxf((float)(end - beg), 1.f);
  unsigned o0 = (unsigned)f2b(a0 * inv) | ((unsigned)f2b(a1 * inv) << 16);
  unsigned o1 = (unsigned)f2b(a2 * inv) | ((unsigned)f2b(a3 * inv) << 16);
  *(uint2*)(hneigh2 + (size_t)node * 256 + 4 * l) = make_uint2(o0, o1);
}

// ---------------- final edge output ----------------
__global__ __launch_bounds__(256) void k_he2(const int* __restrict__ u, const int* __restrict__ v,
                                             const unsigned short* __restrict__ PQ2,
                                             const float* __restrict__ b2e,
                                             float* __restrict__ outp){
  int idx = blockIdx.x * 256 + threadIdx.x;
  int e = idx >> 5;
  if(e >= NE) return;
  int c = (idx & 31) * 4;
  int uu = u[e], vv = v[e];
  uint2 p = *(const uint2*)(PQ2 + (size_t)uu * 256 + c);
  uint2 q = *(const uint2*)(PQ2 + (size_t)vv * 256 + 128 + c);
  float4 b = *(const float4*)(b2e + c);
  float4 r;
  r.x = fmaxf(blo(p.x) + blo(q.x) + b.x, 0.f);
  r.y = fmaxf(bhi(p.x) + bhi(q.x) + b.y, 0.f);
  r.z = fmaxf(blo(p.y) + blo(q.y) + b.z, 0.f);
  r.w = fmaxf(bhi(p.y) + bhi(q.y) + b.w, 0.f);
  *(float4*)(outp + (size_t)e * 128 + c) = r;
}

// ---------------- GEMM: C = [A0|A1] @ B (+bias, relu), bf16 MFMA ----------------
// A segments are bf16 row-major (widths W0, W1, W0+W1 == K). B pre-swizzled.
// Block: 4 waves, 128 rows, 128-col block (grid.y = N/128). Wave: 32 rows x 128 cols.
// OM: 0 = f32 out, 1 = bf16 out, 2 = both.
template<int K, int N, bool BR, int OM>
__global__ __launch_bounds__(256) void k_gemm(const unsigned short* __restrict__ A0, int W0,
                                              const unsigned short* __restrict__ A1, int W1,
                                              const unsigned short* __restrict__ Bs,
                                              const float* __restrict__ bias,
                                              float* __restrict__ Cf,
                                              unsigned short* __restrict__ Cb){
  constexpr int KT  = K / 32;
  constexpr int KTL = (KT > 6) ? 6 : KT;               // <= 61.4 KB LDS
  __shared__ unsigned short Blds[KTL * 128 * 40];
  const int nb   = blockIdx.y;
  const int wid  = threadIdx.x >> 6, lane = threadIdx.x & 63;
  const int ln   = lane & 15, kg = lane >> 4;
  const int r0   = blockIdx.x * 128 + wid * 32;

  floatx4 acc[2][8];
#pragma unroll
  for(int a = 0; a < 2; a++)
#pragma unroll
    for(int b = 0; b < 8; b++) acc[a][b] = (floatx4){0.f, 0.f, 0.f, 0.f};

  for(int kc = 0; kc < KT; kc += KTL){
    __syncthreads();
    constexpr int CH = KTL * 128 * 5;                   // 16B chunks
    for(int cch = threadIdx.x; cch < CH; cch += 256){
      int h  = cch * 8;
      int ls = h / 40;
      int off = h - ls * 40;
      int kt2 = ls >> 7, nl = ls & 127;
      size_t g = ((size_t)((kc + kt2) * N + nb * 128 + nl)) * 40 + off;
      *(short8*)(Blds + h) = *(const short8*)(Bs + g);
    }
    __syncthreads();
#pragma unroll
    for(int kt2 = 0; kt2 < KTL; kt2++){
      int kt = kc + kt2;
      short8 af[2];
#pragma unroll
      for(int mt = 0; mt < 2; mt++){
        int r = r0 + mt * 16 + ln; if(r >= NN) r = NN - 1;
        int k = kt * 32 + kg * 8;
        const unsigned short* p = (k < W0) ? (A0 + (size_t)r * W0 + k)
                                           : (A1 + (size_t)r * W1 + (k - W0));
        af[mt] = *(const short8*)p;
      }
#pragma unroll
      for(int nt = 0; nt < 8; nt++){
        short8 bfrag = *(const short8*)(Blds + ((kt2 * 128 + nt * 16 + ln) * 40 + kg * 8));
        acc[0][nt] = __builtin_amdgcn_mfma_f32_16x16x32_bf16(af[0], bfrag, acc[0][nt], 0, 0, 0);
        acc[1][nt] = __builtin_amdgcn_mfma_f32_16x16x32_bf16(af[1], bfrag, acc[1][nt], 0, 0, 0);
      }
    }
  }
  // epilogue: C/D layout col = lane&15, row = (lane>>4)*4 + reg  [m89/m91 verified]
#pragma unroll
  for(int mt = 0; mt < 2; mt++){
    int rb = r0 + mt * 16 + kg * 4;
#pragma unroll
    for(int nt = 0; nt < 8; nt++){
      int col = nb * 128 + nt * 16 + ln;
      float bv = BR ? bias[col] : 0.f;
#pragma unroll
      for(int rr = 0; rr < 4; rr++){
        int row = rb + rr;
        if(row < NN){
          float vv = acc[mt][nt][rr];
          if(BR) vv = fmaxf(vv + bv, 0.f);
          if(OM == 0 || OM == 2) Cf[(size_t)row * N + col] = vv;
          if(OM == 1 || OM == 2) Cb[(size_t)row * N + col] = f2b(vv);
        }
      }
    }
  }
}

extern "C" void kernel_launch(void* const* d_in, const int* in_sizes, int n_in,
                              void* d_out, int out_size, void* d_ws, size_t ws_size,
                              hipStream_t stream){
  const float* nf  = (const float*)d_in[0];
  const float* ef  = (const float*)d_in[1];
  const float* W1a = (const float*)d_in[2];
  const float* b1a = (const float*)d_in[3];
  const float* W1e = (const float*)d_in[4];
  const float* b1e = (const float*)d_in[5];
  const float* W2a = (const float*)d_in[6];
  const float* b2a = (const float*)d_in[7];
  const float* W2e = (const float*)d_in[8];
  const float* b2e = (const float*)d_in[9];
  const int*   u   = (const int*)d_in[10];
  const int*   v   = (const int*)d_in[11];

  char* ws = (char*)d_ws;
  int* rowptr = (int*)(ws + 0);               // 50001 ints
  int* cnt    = (int*)(ws + 0x40000);         // 50000 ints (hist, then cursor)
  int* part   = (int*)(ws + 0x80000);         // 98 ints
  unsigned short* w1as = (unsigned short*)(ws + 0x90000);
  unsigned short* w1es = (unsigned short*)(ws + 0xA0000);
  unsigned short* w2as = (unsigned short*)(ws + 0xC0000);
  unsigned short* w2es = (unsigned short*)(ws + 0xE0000);
  unsigned short* nfb  = (unsigned short*)(ws + (size_t)(1u  << 20));  // 6.4 MB
  int2*           ebuf = (int2*)          (ws + (size_t)(8u  << 20));  // 6.4 MB
  unsigned short* hn1b = (unsigned short*)(ws + (size_t)(15u << 20));  // 12.8 MB
  unsigned short* hn2b = (unsigned short*)(ws + (size_t)(28u << 20));  // 12.8 MB
  unsigned short* PQ   = (unsigned short*)(ws + (size_t)(41u << 20));  // 25.6 MB
  unsigned short* hnb1 = (unsigned short*)(ws + (size_t)(67u << 20));  // 12.8 MB
  unsigned short* hnb2 = (unsigned short*)(ws + (size_t)(80u << 20));  // 25.6 MB

  hipMemsetAsync(ws + 0x40000, 0, 0x40200, stream);   // zero cnt + part

  // CSR build
  k_hist <<<3125, 256, 0, stream>>>(v, cnt);
  k_scanA<<<98,   512, 0, stream>>>(cnt, rowptr, part);
  k_scanB<<<1,    64,  0, stream>>>(part, rowptr);
  k_scanC<<<98,   512, 0, stream>>>(rowptr, part, cnt);
  k_fill <<<3125, 256, 0, stream>>>(u, v, cnt, ebuf);

  // prep: nfeats->bf16, weights->swizzled bf16
  k_cvt4<<<3125, 256, 0, stream>>>((const float4*)nf, nfb, NN * 64 / 4);
  k_wswz_dir <<<(192 * 128 + 255) / 256, 256, 0, stream>>>(W1a, w1as, 192, 128);
  k_wswz_edge<<<128, 256, 0, stream>>>(W1e, w1es);
  k_wswz_dir <<<(384 * 128 + 255) / 256, 256, 0, stream>>>(W2a, w2as, 384, 128);
  k_wswz_edge<<<128, 256, 0, stream>>>(W2e, w2es);

  // layer 1
  k_agg1<<<12500, 256, 0, stream>>>(rowptr, ebuf, nfb, ef, hnb1);
  k_gemm<192, 128, true,  1><<<dim3(391, 1), 256, 0, stream>>>(nfb, 64, hnb1, 128, w1as, b1a, nullptr, hn1b);
  k_gemm<128, 256, false, 1><<<dim3(391, 2), 256, 0, stream>>>(hn1b, 128, hn1b, 128, w1es, nullptr, nullptr, PQ);

  // layer 2
  k_agg2<<<12500, 256, 0, stream>>>(rowptr, ebuf, hn1b, PQ, b1e, hnb2);
  k_gemm<384, 128, true,  2><<<dim3(391, 1), 256, 0, stream>>>(hn1b, 128, hnb2, 256, w2as, b2a, (float*)d_out, hn2b);
  k_gemm<128, 256, false, 1><<<dim3(391, 2), 256, 0, stream>>>(hn2b, 128, hn2b, 128, w2es, nullptr, nullptr, PQ);
  k_he2<<<100000, 256, 0, stream>>>(u, v, PQ, b2e, (float*)d_out + (size_t)NN * 128);
}

// Round 2
// 1020.450 us; speedup vs baseline: 1.1330x; 1.1330x over previous
//
#include <hip/hip_runtime.h>

#define NN 50000
#define NE 800000

typedef __attribute__((ext_vector_type(8))) short short8;
typedef __attribute__((ext_vector_type(4))) float floatx4;

__device__ __forceinline__ unsigned short f2b(float f){
  unsigned u = __float_as_uint(f);
  u += 0x7fffu + ((u >> 16) & 1u);
  return (unsigned short)(u >> 16);
}
__device__ __forceinline__ float blo(unsigned u){ return __uint_as_float(u << 16); }
__device__ __forceinline__ float bhi(unsigned u){ return __uint_as_float(u & 0xffff0000u); }

// ---------------- fused prep: ef->bf16, nf->bf16, hist, weight swizzles ----------------
// packed B layout (stride 32): dst[((k>>5)*N + n)*32 + (k&31)]
#define NB_EF   50000          // NE*64/4 float4 / 256
#define NB_NF   3125           // NN*64/4 float4 / 256
#define NB_HIST 3125           // NE/256
#define NB_W1A  96             // 192*128/256
#define NB_W1E  128            // 128*256/256
#define NB_W2A  192            // 384*128/256
#define NB_W2E  128

__global__ __launch_bounds__(256) void k_prep(const float* __restrict__ nf,
                                              const float* __restrict__ ef,
                                              const float* __restrict__ W1a,
                                              const float* __restrict__ W1e,
                                              const float* __restrict__ W2a,
                                              const float* __restrict__ W2e,
                                              const int* __restrict__ v,
                                              unsigned short* __restrict__ nfb,
                                              unsigned short* __restrict__ efb,
                                              unsigned short* __restrict__ w1as,
                                              unsigned short* __restrict__ w1es,
                                              unsigned short* __restrict__ w2as,
                                              unsigned short* __restrict__ w2es,
                                              int* __restrict__ cnt){
  int b = blockIdx.x, t = threadIdx.x;
  if(b < NB_EF){
    int i = b * 256 + t;
    float4 vv = ((const float4*)ef)[i];
    unsigned a = (unsigned)f2b(vv.x) | ((unsigned)f2b(vv.y) << 16);
    unsigned c = (unsigned)f2b(vv.z) | ((unsigned)f2b(vv.w) << 16);
    ((uint2*)efb)[i] = make_uint2(a, c);
  } else if(b < NB_EF + NB_NF){
    int i = (b - NB_EF) * 256 + t;
    float4 vv = ((const float4*)nf)[i];
    unsigned a = (unsigned)f2b(vv.x) | ((unsigned)f2b(vv.y) << 16);
    unsigned c = (unsigned)f2b(vv.z) | ((unsigned)f2b(vv.w) << 16);
    ((uint2*)nfb)[i] = make_uint2(a, c);
  } else if(b < NB_EF + NB_NF + NB_HIST){
    int e = (b - NB_EF - NB_NF) * 256 + t;
    if(e < NE) atomicAdd(&cnt[v[e]], 1);
  } else if(b < NB_EF + NB_NF + NB_HIST + NB_W1A){
    int i = (b - NB_EF - NB_NF - NB_HIST) * 256 + t;        // 192x128
    int k = i >> 7, n = i & 127;
    w1as[((k >> 5) * 128 + n) * 32 + (k & 31)] = f2b(W1a[i]);
  } else if(b < NB_EF + NB_NF + NB_HIST + NB_W1A + NB_W1E){
    int i = (b - NB_EF - NB_NF - NB_HIST - NB_W1A) * 256 + t; // 128x256 view of 256x128
    int k = i >> 8, n = i & 255;
    float val = W1e[(size_t)(k + ((n >> 7) << 7)) * 128 + (n & 127)];
    w1es[((k >> 5) * 256 + n) * 32 + (k & 31)] = f2b(val);
  } else if(b < NB_EF + NB_NF + NB_HIST + NB_W1A + NB_W1E + NB_W2A){
    int i = (b - NB_EF - NB_NF - NB_HIST - NB_W1A - NB_W1E) * 256 + t; // 384x128
    int k = i >> 7, n = i & 127;
    w2as[((k >> 5) * 128 + n) * 32 + (k & 31)] = f2b(W2a[i]);
  } else {
    int i = (b - NB_EF - NB_NF - NB_HIST - NB_W1A - NB_W1E - NB_W2A) * 256 + t;
    int k = i >> 8, n = i & 255;
    float val = W2e[(size_t)(k + ((n >> 7) << 7)) * 128 + (n & 127)];
    w2es[((k >> 5) * 256 + n) * 32 + (k & 31)] = f2b(val);
  }
}

// ---------------- CSR scan + fill ----------------
__global__ __launch_bounds__(512) void k_scanA(const int* __restrict__ cnt,
                                               int* __restrict__ rowptr,
                                               int* __restrict__ part){
  __shared__ int lds[512];
  int t = threadIdx.x;
  int i = blockIdx.x * 512 + t;
  int x = (i < NN) ? cnt[i] : 0;
  lds[t] = x;
  __syncthreads();
  for(int o = 1; o < 512; o <<= 1){
    int y = (t >= o) ? lds[t - o] : 0;
    __syncthreads();
    lds[t] += y;
    __syncthreads();
  }
  if(i < NN) rowptr[i] = lds[t] - x;
  if(t == 511) part[blockIdx.x] = lds[511];
}

__global__ void k_scanB(int* __restrict__ part, int* __restrict__ rowptr){
  if(threadIdx.x == 0 && blockIdx.x == 0){
    int run = 0;
    for(int b = 0; b < 98; b++){ int tt = part[b]; part[b] = run; run += tt; }
    rowptr[NN] = run;
  }
}

__global__ __launch_bounds__(512) void k_scanC(int* __restrict__ rowptr,
                                               const int* __restrict__ part,
                                               int* __restrict__ cursor){
  int i = blockIdx.x * 512 + threadIdx.x;
  if(i < NN){
    int val = rowptr[i] + part[blockIdx.x];
    rowptr[i] = val;
    cursor[i] = val;
  }
}

__global__ __launch_bounds__(256) void k_fill(const int* __restrict__ u, const int* __restrict__ v,
                                              int* __restrict__ cursor, int2* __restrict__ ebuf){
  int e = blockIdx.x * 256 + threadIdx.x;
  if(e < NE){
    int pos = atomicAdd(&cursor[v[e]], 1);
    ebuf[pos] = make_int2(u[e], e);
  }
}

// ---------------- layer-1 aggregation (uniform loop) ----------------
// msg cols: [0,64) = nfb[src], [64,128) = efb[edge]. 64 lanes/node, 2 cols/lane.
__global__ __launch_bounds__(256) void k_agg1(const int* __restrict__ rowptr,
                                              const int2* __restrict__ ebuf,
                                              const unsigned short* __restrict__ nfb,
                                              const unsigned short* __restrict__ efb,
                                              unsigned short* __restrict__ hneigh1){
  int node = blockIdx.x * 4 + (threadIdx.x >> 6);
  int l = threadIdx.x & 63;
  int beg = rowptr[node], end = rowptr[node + 1];
  bool sel = l >= 32;
  const unsigned short* base = sel ? (efb + 2 * (l - 32)) : (nfb + 2 * l);
  float a0 = 0.f, a1 = 0.f;
  for(int i = beg; i < end; i++){
    int2 e = ebuf[i];
    int idx = sel ? e.y : e.x;
    unsigned t = *(const unsigned*)(base + (size_t)((unsigned)idx * 64u));
    a0 += blo(t); a1 += bhi(t);
  }
  float inv = 1.f / fmaxf((float)(end - beg), 1.f);
  unsigned o = (unsigned)f2b(a0 * inv) | ((unsigned)f2b(a1 * inv) << 16);
  *(unsigned*)(hneigh1 + (size_t)node * 128 + 2 * l) = o;
}

// ---------------- layer-2 aggregation (uniform loop) ----------------
// msg cols: [0,128) = hn1[src], [128,256) = relu(P1[src]+Q1[node]+b1e). 4 cols/lane.
__global__ __launch_bounds__(256) void k_agg2(const int* __restrict__ rowptr,
                                              const int2* __restrict__ ebuf,
                                              const unsigned short* __restrict__ hn1,
                                              const unsigned short* __restrict__ PQ1,
                                              const float* __restrict__ b1e,
                                              unsigned short* __restrict__ hneigh2){
  int node = blockIdx.x * 4 + (threadIdx.x >> 6);
  int l = threadIdx.x & 63;
  int beg = rowptr[node], end = rowptr[node + 1];
  bool sel = l >= 32;
  int c4 = sel ? 4 * (l - 32) : 4 * l;
  const unsigned short* base = sel ? (PQ1 + c4) : (hn1 + c4);
  unsigned stride = sel ? 256u : 128u;
  float q0 = 0.f, q1 = 0.f, q2 = 0.f, q3 = 0.f, fl = -__builtin_inff();
  if(sel){
    uint2 qq = *(const uint2*)(PQ1 + (size_t)node * 256 + 128 + c4);
    q0 = blo(qq.x) + b1e[c4];
    q1 = bhi(qq.x) + b1e[c4 + 1];
    q2 = blo(qq.y) + b1e[c4 + 2];
    q3 = bhi(qq.y) + b1e[c4 + 3];
    fl = 0.f;
  }
  float a0 = 0.f, a1 = 0.f, a2 = 0.f, a3 = 0.f;
  for(int i = beg; i < end; i++){
    unsigned s = (unsigned)ebuf[i].x;
    uint2 t = *(const uint2*)(base + (size_t)(s * stride));
    a0 += fmaxf(blo(t.x) + q0, fl);
    a1 += fmaxf(bhi(t.x) + q1, fl);
    a2 += fmaxf(blo(t.y) + q2, fl);
    a3 += fmaxf(bhi(t.y) + q3, fl);
  }
  float inv = 1.f / fmaxf((float)(end - beg), 1.f);
  unsigned o0 = (unsigned)f2b(a0 * inv) | ((unsigned)f2b(a1 * inv) << 16);
  unsigned o1 = (unsigned)f2b(a2 * inv) | ((unsigned)f2b(a3 * inv) << 16);
  *(uint2*)(hneigh2 + (size_t)node * 256 + 4 * l) = make_uint2(o0, o1);
}

// ---------------- final edge output ----------------
__global__ __launch_bounds__(256) void k_he2(const int* __restrict__ u, const int* __restrict__ v,
                                             const unsigned short* __restrict__ PQ2,
                                             const float* __restrict__ b2e,
                                             float* __restrict__ outp){
  int idx = blockIdx.x * 256 + threadIdx.x;
  int e = idx >> 5;
  if(e >= NE) return;
  int c = (idx & 31) * 4;
  int uu = u[e], vv = v[e];
  uint2 p = *(const uint2*)(PQ2 + (size_t)uu * 256 + c);
  uint2 q = *(const uint2*)(PQ2 + (size_t)vv * 256 + 128 + c);
  float4 b = *(const float4*)(b2e + c);
  float4 r;
  r.x = fmaxf(blo(p.x) + blo(q.x) + b.x, 0.f);
  r.y = fmaxf(bhi(p.x) + bhi(q.x) + b.y, 0.f);
  r.z = fmaxf(blo(p.y) + blo(q.y) + b.z, 0.f);
  r.w = fmaxf(bhi(p.y) + bhi(q.y) + b.w, 0.f);
  *(float4*)(outp + (size_t)e * 128 + c) = r;
}

// ---------------- GEMM: C = [A0|A1] @ B (+bias, relu), bf16 MFMA, LDS-free ----------------
// B packed layout (stride 32), B panels are small (<=96KB) and L2-resident: load
// fragments straight from global. No barriers, no LDS -> max occupancy.
// Block: 4 waves, 128 rows; grid.y = N/128 col blocks. Wave: 32 rows x 128 cols.
// OM: 0 = f32 out, 1 = bf16 out, 2 = both.
template<int K, int N, bool BR, int OM>
__global__ __launch_bounds__(256) void k_gemm(const unsigned short* __restrict__ A0, int W0,
                                              const unsigned short* __restrict__ A1, int W1,
                                              const unsigned short* __restrict__ Bs,
                                              const float* __restrict__ bias,
                                              float* __restrict__ Cf,
                                              unsigned short* __restrict__ Cb){
  constexpr int KT = K / 32;
  const int nb = blockIdx.y;
  const int wid = threadIdx.x >> 6, lane = threadIdx.x & 63;
  const int ln = lane & 15, kg = lane >> 4;
  const int r0 = blockIdx.x * 128 + wid * 32;
  int r_[2];
  r_[0] = min(r0 + ln, NN - 1);
  r_[1] = min(r0 + 16 + ln, NN - 1);

  floatx4 acc[2][8];
#pragma unroll
  for(int a = 0; a < 2; a++)
#pragma unroll
    for(int b = 0; b < 8; b++) acc[a][b] = (floatx4){0.f, 0.f, 0.f, 0.f};

#pragma unroll
  for(int kt = 0; kt < KT; kt++){
    int k = kt * 32 + kg * 8;
    short8 af[2];
#pragma unroll
    for(int mt = 0; mt < 2; mt++){
      const unsigned short* p = (k < W0) ? (A0 + (size_t)r_[mt] * W0 + k)
                                         : (A1 + (size_t)r_[mt] * W1 + (k - W0));
      af[mt] = *(const short8*)p;
    }
    const unsigned short* bp = Bs + ((size_t)(kt * N + nb * 128)) * 32 + kg * 8;
#pragma unroll
    for(int nt = 0; nt < 8; nt++){
      short8 bfrag = *(const short8*)(bp + (nt * 16 + ln) * 32);
      acc[0][nt] = __builtin_amdgcn_mfma_f32_16x16x32_bf16(af[0], bfrag, acc[0][nt], 0, 0, 0);
      acc[1][nt] = __builtin_amdgcn_mfma_f32_16x16x32_bf16(af[1], bfrag, acc[1][nt], 0, 0, 0);
    }
  }
  // epilogue: C/D layout col = lane&15, row = (lane>>4)*4 + reg  [m89/m91 verified]
#pragma unroll
  for(int mt = 0; mt < 2; mt++){
    int rb = r0 + mt * 16 + kg * 4;
#pragma unroll
    for(int nt = 0; nt < 8; nt++){
      int col = nb * 128 + nt * 16 + ln;
      float bv = BR ? bias[col] : 0.f;
#pragma unroll
      for(int rr = 0; rr < 4; rr++){
        int row = rb + rr;
        if(row < NN){
          float vv = acc[mt][nt][rr];
          if(BR) vv = fmaxf(vv + bv, 0.f);
          if(OM == 0 || OM == 2) Cf[(size_t)row * N + col] = vv;
          if(OM == 1 || OM == 2) Cb[(size_t)row * N + col] = f2b(vv);
        }
      }
    }
  }
}

extern "C" void kernel_launch(void* const* d_in, const int* in_sizes, int n_in,
                              void* d_out, int out_size, void* d_ws, size_t ws_size,
                              hipStream_t stream){
  const float* nf  = (const float*)d_in[0];
  const float* ef  = (const float*)d_in[1];
  const float* W1a = (const float*)d_in[2];
  const float* b1a = (const float*)d_in[3];
  const float* W1e = (const float*)d_in[4];
  const float* b1e = (const float*)d_in[5];
  const float* W2a = (const float*)d_in[6];
  const float* b2a = (const float*)d_in[7];
  const float* W2e = (const float*)d_in[8];
  const float* b2e = (const float*)d_in[9];
  const int*   u   = (const int*)d_in[10];
  const int*   v   = (const int*)d_in[11];

  char* ws = (char*)d_ws;
  int* rowptr = (int*)(ws + 0);               // 50001 ints
  int* cnt    = (int*)(ws + 0x40000);         // 50000 ints (hist, then cursor)
  int* part   = (int*)(ws + 0x80000);         // 98 ints
  unsigned short* w1as = (unsigned short*)(ws + 0x90000);   // 48 KB
  unsigned short* w1es = (unsigned short*)(ws + 0xA0000);   // 64 KB
  unsigned short* w2as = (unsigned short*)(ws + 0xC0000);   // 96 KB
  unsigned short* w2es = (unsigned short*)(ws + 0xE0000);   // 64 KB
  unsigned short* nfb  = (unsigned short*)(ws + (size_t)(1u   << 20));  // 6.4 MB
  int2*           ebuf = (int2*)          (ws + (size_t)(8u   << 20));  // 6.4 MB
  unsigned short* hn1b = (unsigned short*)(ws + (size_t)(15u  << 20));  // 12.8 MB
  unsigned short* hn2b = (unsigned short*)(ws + (size_t)(28u  << 20));  // 12.8 MB
  unsigned short* PQ   = (unsigned short*)(ws + (size_t)(41u  << 20));  // 25.6 MB
  unsigned short* hnb1 = (unsigned short*)(ws + (size_t)(67u  << 20));  // 12.8 MB
  unsigned short* hnb2 = (unsigned short*)(ws + (size_t)(80u  << 20));  // 25.6 MB
  unsigned short* efb  = (unsigned short*)(ws + (size_t)(106u << 20));  // 102.4 MB

  hipMemsetAsync(ws + 0x40000, 0, 0x40200, stream);   // zero cnt + part

  // fused prep: ef/nf -> bf16, histogram, weight swizzles
  k_prep<<<NB_EF + NB_NF + NB_HIST + NB_W1A + NB_W1E + NB_W2A + NB_W2E, 256, 0, stream>>>(
      nf, ef, W1a, W1e, W2a, W2e, v, nfb, efb, w1as, w1es, w2as, w2es, cnt);

  // CSR
  k_scanA<<<98, 512, 0, stream>>>(cnt, rowptr, part);
  k_scanB<<<1,  64,  0, stream>>>(part, rowptr);
  k_scanC<<<98, 512, 0, stream>>>(rowptr, part, cnt);
  k_fill <<<3125, 256, 0, stream>>>(u, v, cnt, ebuf);

  // layer 1
  k_agg1<<<12500, 256, 0, stream>>>(rowptr, ebuf, nfb, efb, hnb1);
  k_gemm<192, 128, true,  1><<<dim3(391, 1), 256, 0, stream>>>(nfb, 64, hnb1, 128, w1as, b1a, nullptr, hn1b);
  k_gemm<128, 256, false, 1><<<dim3(391, 2), 256, 0, stream>>>(hn1b, 128, hn1b, 128, w1es, nullptr, nullptr, PQ);

  // layer 2
  k_agg2<<<12500, 256, 0, stream>>>(rowptr, ebuf, hn1b, PQ, b1e, hnb2);
  k_gemm<384, 128, true,  2><<<dim3(391, 1), 256, 0, stream>>>(hn1b, 128, hnb2, 256, w2as, b2a, (float*)d_out, hn2b);
  k_gemm<128, 256, false, 1><<<dim3(391, 2), 256, 0, stream>>>(hn2b, 128, hn2b, 128, w2es, nullptr, nullptr, PQ);
  k_he2<<<100000, 256, 0, stream>>>(u, v, PQ, b2e, (float*)d_out + (size_t)NN * 128);
}